// Round 10
// baseline (219.018 us; speedup 1.0000x reference)
//
#include <hip/hip_runtime.h>

#define BOUND 1e-6f
#define HALF_PI 1.57079632679489662f
#define LOG2E 1.44269504088896341f

// DPP helper: masked/out-of-range lanes receive `oldv` (1.0 = mult identity).
#define UPD_DPP(oldv, srcv, ctrl, rmask)                                        \
  __int_as_float(__builtin_amdgcn_update_dpp(                                   \
      __float_as_int(oldv), __float_as_int(srcv), (ctrl), (rmask), 0xF, false))

// Inclusive multiplicative scan across 64 lanes, pure VALU (validated R2-R9).
__device__ __forceinline__ float wave_incl_prod(float x) {
    x *= UPD_DPP(1.0f, x, 0x111, 0xF);  // row_shr:1
    x *= UPD_DPP(1.0f, x, 0x112, 0xF);  // row_shr:2
    x *= UPD_DPP(1.0f, x, 0x114, 0xF);  // row_shr:4
    x *= UPD_DPP(1.0f, x, 0x118, 0xF);  // row_shr:8
    x *= UPD_DPP(1.0f, x, 0x142, 0xA);  // row_bcast:15 -> rows 1,3
    x *= UPD_DPP(1.0f, x, 0x143, 0xC);  // row_bcast:31 -> rows 2,3
    return x;
}

// PERSISTENT double-buffered pipeline. 1024 blocks (4/CU, exactly resident)
// x 256 threads; each block loops over chunks of 16 rows (stride gridDim).
// Per chunk: prefetch next chunk's x into regs -> compute current chunk into
// LDS[cur] -> {s_waitcnt lgkmcnt(0); s_barrier} (ONE asm: no vmcnt drain, so
// prefetch loads + prior global stores stay in flight across the barrier) ->
// cooperative 16B/lane 64B-sector-aligned stores from LDS. This removes the
// per-block load-latency exposure + phase serialization that R8->R9's grain
// halving only partially addressed. Per-wave math identical to R9.
// out[j]   = radius * prod_{i<j}(sin(a_i)+B) * (cos(a_j)+B),  j < 256
// out[256] = radius * prod_{i<256}(sin(a_i)+B)
__global__ __launch_bounds__(256) void spherize_kernel(
    const float* __restrict__ x,
    const float* __restrict__ p_phiL,
    const float* __restrict__ p_radius,
    const float* __restrict__ p_scaling,
    float* __restrict__ out,
    int n_rows, int nchunks)
{
    __shared__ float lds[2][16 * 257];   // 2 x 16448 B

    const float phi_L   = p_phiL[0];
    const float radius  = p_radius[0];
    const float cexp    = p_scaling[0] * LOG2E;  // exp(s*x) = exp2(cexp*x)
    const float amp     = HALF_PI - phi_L;

    const int tid    = threadIdx.x;
    const int lane   = tid & 63;
    const int wave   = tid >> 6;          // 0..3
    const int stride = gridDim.x;

    // ---- load one chunk's 4 rows for this wave into regs ----
    auto LOADC = [&](float4 (&r)[4], int c) {
        const int wrow = c * 16 + wave * 4;
        const float* xb = x + (size_t)wrow * 256 + lane * 4;
        #pragma unroll
        for (int i = 0; i < 4; ++i)
            if (wrow + i < n_rows)
                r[i] = *reinterpret_cast<const float4*>(xb + i * 256);
    };

    // ---- compute one chunk into an LDS buffer, then waitcnt+barrier ----
    auto COMPUTE = [&](float4 (&r)[4], int c, float* buf) {
        const int wrow = c * 16 + wave * 4;
        #pragma unroll
        for (int i = 0; i < 4; ++i) {
            if (wrow + i >= n_rows) break;
            const float* xp = &r[i].x;
            float s[4], cc[4];
            #pragma unroll
            for (int k = 0; k < 4; ++k) {
                // u = pi/2 - a = amp / (1 + exp(s*x))
                float e  = __builtin_amdgcn_exp2f(cexp * xp[k]);
                float u  = amp * __builtin_amdgcn_rcpf(1.0f + e);
                float u2 = u * u;
                s[k] = fmaf(u2, fmaf(u2, 4.16666667e-2f, -0.5f), 1.0f + BOUND);
                float p = fmaf(u2, fmaf(u2, 8.33333333e-3f, -1.66666667e-1f), 1.0f);
                cc[k] = fmaf(u, p, BOUND);
            }
            float q1 = s[0];
            float q2 = q1 * s[1];
            float q3 = q2 * s[2];
            float t  = q3 * s[3];
            float scan = wave_incl_prod(t);               // inclusive over lanes
            float excl = UPD_DPP(1.0f, scan, 0x138, 0xF); // wave_shr:1, lane0=1
            float base = radius * excl;

            float* lrow = buf + (wave * 4 + i) * 257 + lane * 4;
            lrow[0] = base * cc[0];
            lrow[1] = base * q1 * cc[1];
            lrow[2] = base * q2 * cc[2];
            lrow[3] = base * q3 * cc[3];
            if (lane == 63)
                lrow[4] = radius * scan;                  // col 256
        }
        // LDS visible to block; do NOT drain vmcnt (prefetch/stores in flight)
        asm volatile("s_waitcnt lgkmcnt(0)\n\ts_barrier" ::: "memory");
    };

    // ---- cooperative store of one chunk's LDS region (64B-sector aligned) --
    auto STOREC = [&](int c, const float* buf) {
        const int row0 = c * 16;
        float* obase = out + (size_t)row0 * 257;
        const int nrb = min(16, n_rows - row0);
        if (nrb == 16) {
            // 16*257 = 4112 dwords = 1028 float4
            const float4* l4 = reinterpret_cast<const float4*>(buf);
            float4*       o4 = reinterpret_cast<float4*>(obase);
            o4[tid]       = l4[tid];
            o4[tid + 256] = l4[tid + 256];
            o4[tid + 512] = l4[tid + 512];
            o4[tid + 768] = l4[tid + 768];
            if (tid < 4) o4[tid + 1024] = l4[tid + 1024];
        } else {
            const int nd = nrb * 257;
            for (int i = tid; i < nd; i += 256) obase[i] = buf[i];
        }
    };

    int c = blockIdx.x;
    if (c >= nchunks) return;

    float4 xA[4], xB[4];
    LOADC(xA, c);
    for (;;) {
        const int c1 = c + stride;
        if (c1 < nchunks) LOADC(xB, c1);        // prefetch under compute+store
        COMPUTE(xA, c, lds[0]);
        STOREC(c, lds[0]);
        if (c1 >= nchunks) break;
        const int c2 = c1 + stride;
        if (c2 < nchunks) LOADC(xA, c2);
        COMPUTE(xB, c1, lds[1]);
        STOREC(c1, lds[1]);
        if (c2 >= nchunks) break;
        c = c2;
    }
}

extern "C" void kernel_launch(void* const* d_in, const int* in_sizes, int n_in,
                              void* d_out, int out_size, void* d_ws, size_t ws_size,
                              hipStream_t stream) {
    // inputs: 0=x [N,256], 1=W_theta, 2=W_phi, 3=b_phi, 4=phi_L, 5=radius, 6=scaling
    const float* x         = (const float*)d_in[0];
    const float* p_phiL    = (const float*)d_in[4];
    const float* p_radius  = (const float*)d_in[5];
    const float* p_scaling = (const float*)d_in[6];
    float* out = (float*)d_out;

    const int n_rows  = in_sizes[0] / 256;
    const int nchunks = (n_rows + 15) / 16;      // 32768 for N=524288
    int blocks = 1024;                           // 4 blocks/CU, exactly resident
    if (blocks > nchunks) blocks = nchunks;

    spherize_kernel<<<blocks, 256, 0, stream>>>(x, p_phiL, p_radius, p_scaling,
                                                out, n_rows, nchunks);
}

// Round 11
// 216.443 us; speedup vs baseline: 1.0119x; 1.0119x over previous
//
#include <hip/hip_runtime.h>

#define BOUND 1e-6f
#define HALF_PI 1.57079632679489662f
#define LOG2E 1.44269504088896341f

// DPP helper: masked/out-of-range lanes receive `oldv` (1.0 = mult identity).
#define UPD_DPP(oldv, srcv, ctrl, rmask)                                        \
  __int_as_float(__builtin_amdgcn_update_dpp(                                   \
      __float_as_int(oldv), __float_as_int(srcv), (ctrl), (rmask), 0xF, false))

// Inclusive multiplicative scan across 64 lanes, pure VALU (validated R2-R10).
__device__ __forceinline__ float wave_incl_prod(float x) {
    x *= UPD_DPP(1.0f, x, 0x111, 0xF);  // row_shr:1
    x *= UPD_DPP(1.0f, x, 0x112, 0xF);  // row_shr:2
    x *= UPD_DPP(1.0f, x, 0x114, 0xF);  // row_shr:4
    x *= UPD_DPP(1.0f, x, 0x118, 0xF);  // row_shr:8
    x *= UPD_DPP(1.0f, x, 0x142, 0xA);  // row_bcast:15 -> rows 1,3
    x *= UPD_DPP(1.0f, x, 0x143, 0xC);  // row_bcast:31 -> rows 2,3
    return x;
}

// WAVE-AUTONOMOUS barrier-free pipeline (R10 post-mortem: pipelining must be
// wave-grain, not block-grain). Each wave owns 4-row groups, grid-strided by
// total_waves (dense instantaneous footprint). Per group: register-prefetch
// next group's 4KB -> compute current (R9 math) -> stage into this wave's
// PRIVATE 4112B LDS slice -> lgkmcnt(0) (wave-local; same-wave DS ops are
// in-order, so the single buffer is WAR-safe) -> read back as float4 ->
// 4 x 1024B contiguous stores (+1 tail float4). NO __syncthreads anywhere,
// no vmcnt drains: every wave keeps reads in flight continuously under
// compute+store, which is what the block-lifecycle structure (R5-R9) lacked
// vs a pure copy (5.27 vs 6.29 TB/s).
// out[j]   = radius * prod_{i<j}(sin(a_i)+B) * (cos(a_j)+B),  j < 256
// out[256] = radius * prod_{i<256}(sin(a_i)+B)
__global__ __launch_bounds__(256) void spherize_kernel(
    const float* __restrict__ x,
    const float* __restrict__ p_phiL,
    const float* __restrict__ p_radius,
    const float* __restrict__ p_scaling,
    float* __restrict__ out,
    int n_rows, int n_groups, int total_waves)
{
    __shared__ float lds[4 * 1028];   // 4 waves x 1028 dwords (4112 B each)

    const float phi_L  = p_phiL[0];
    const float radius = p_radius[0];
    const float cexp   = p_scaling[0] * LOG2E;  // exp(s*x) = exp2(cexp*x)
    const float amp    = HALF_PI - phi_L;

    const int lane = threadIdx.x & 63;
    const int wave = threadIdx.x >> 6;          // 0..3
    float* myl = lds + wave * 1028;             // this wave's private slice

    // ---- load one 4-row group into registers (float4, 1KB/instr) ----
    auto LOADG = [&](float4 (&r)[4], int g) {
        const int r0 = g * 4;
        const float* xb = x + (size_t)r0 * 256 + lane * 4;
        #pragma unroll
        for (int i = 0; i < 4; ++i)
            if (r0 + i < n_rows)
                r[i] = *reinterpret_cast<const float4*>(xb + i * 256);
    };

    // ---- compute one group, stage through private LDS, store (no barrier) --
    auto PROC = [&](const float4 (&r)[4], int g) {
        const int r0 = g * 4;
        const int nr = min(4, n_rows - r0);
        #pragma unroll
        for (int i = 0; i < 4; ++i) {
            if (i >= nr) break;
            const float* xp = &r[i].x;
            float s[4], cc[4];
            #pragma unroll
            for (int k = 0; k < 4; ++k) {
                // u = pi/2 - a = amp / (1 + exp(s*x))
                float e  = __builtin_amdgcn_exp2f(cexp * xp[k]);
                float u  = amp * __builtin_amdgcn_rcpf(1.0f + e);
                float u2 = u * u;
                s[k] = fmaf(u2, fmaf(u2, 4.16666667e-2f, -0.5f), 1.0f + BOUND);
                float p = fmaf(u2, fmaf(u2, 8.33333333e-3f, -1.66666667e-1f), 1.0f);
                cc[k] = fmaf(u, p, BOUND);
            }
            float q1 = s[0];
            float q2 = q1 * s[1];
            float q3 = q2 * s[2];
            float t  = q3 * s[3];
            float scan = wave_incl_prod(t);               // inclusive over lanes
            float excl = UPD_DPP(1.0f, scan, 0x138, 0xF); // wave_shr:1, lane0=1
            float base = radius * excl;

            float* lrow = myl + i * 257 + lane * 4;
            lrow[0] = base * cc[0];
            lrow[1] = base * q1 * cc[1];
            lrow[2] = base * q2 * cc[2];
            lrow[3] = base * q3 * cc[3];
            if (lane == 63)
                lrow[4] = radius * scan;                  // col 256
        }
        // wave-local LDS visibility; no s_barrier, no vmcnt drain
        asm volatile("s_waitcnt lgkmcnt(0)" ::: "memory");

        float* obase = out + (size_t)r0 * 257;
        if (nr == 4) {
            // group region = 4112 B contiguous, 16B-aligned: 257 float4s
            const float4* l4 = reinterpret_cast<const float4*>(myl);
            float4*       o4 = reinterpret_cast<float4*>(obase);
            o4[lane]       = l4[lane];
            o4[lane + 64]  = l4[lane + 64];
            o4[lane + 128] = l4[lane + 128];
            o4[lane + 192] = l4[lane + 192];
            if (lane == 0) o4[256] = l4[256];
        } else {
            const int nd = nr * 257;
            for (int j = lane; j < nd; j += 64) obase[j] = myl[j];
        }
    };

    int g = blockIdx.x * 4 + wave;              // global wave id = first group
    if (g >= n_groups) return;

    float4 A[4], B[4];
    LOADG(A, g);
    for (;;) {
        const int g1 = g + total_waves;
        if (g1 < n_groups) LOADG(B, g1);        // prefetch under PROC(A)
        PROC(A, g);
        if (g1 >= n_groups) break;
        const int g2 = g1 + total_waves;
        if (g2 < n_groups) LOADG(A, g2);        // prefetch under PROC(B)
        PROC(B, g1);
        if (g2 >= n_groups) break;
        g = g2;
    }
}

extern "C" void kernel_launch(void* const* d_in, const int* in_sizes, int n_in,
                              void* d_out, int out_size, void* d_ws, size_t ws_size,
                              hipStream_t stream) {
    // inputs: 0=x [N,256], 1=W_theta, 2=W_phi, 3=b_phi, 4=phi_L, 5=radius, 6=scaling
    const float* x         = (const float*)d_in[0];
    const float* p_phiL    = (const float*)d_in[4];
    const float* p_radius  = (const float*)d_in[5];
    const float* p_scaling = (const float*)d_in[6];
    float* out = (float*)d_out;

    const int n_rows   = in_sizes[0] / 256;
    const int n_groups = (n_rows + 3) / 4;       // 131072 for N=524288
    int blocks = 2048;                           // 8192 waves; 16 groups/wave
    if (blocks * 4 > n_groups) blocks = (n_groups + 3) / 4;
    const int total_waves = blocks * 4;

    spherize_kernel<<<blocks, 256, 0, stream>>>(x, p_phiL, p_radius, p_scaling,
                                                out, n_rows, n_groups, total_waves);
}